// Round 20
// baseline (109.594 us; speedup 1.0000x reference)
//
#include <hip/hip_runtime.h>
#include <hip/hip_bf16.h>
#include <stdint.h>

typedef unsigned short u16;
typedef __attribute__((ext_vector_type(8))) short bf16x8;
typedef __attribute__((ext_vector_type(4))) float f32x4;
typedef __attribute__((ext_vector_type(16))) float f32x16;

typedef __attribute__((address_space(1))) const void gas_t;
typedef __attribute__((address_space(3))) void las_t;

#define DEV __device__ __forceinline__

DEV float bf2f(u16 v){ union{uint32_t u; float f;} x; x.u = ((uint32_t)v)<<16; return x.f; }
DEV u16 f2bf(float f){ union{float f; uint32_t u;} x; x.f=f; uint32_t r = x.u + 0x7fff + ((x.u>>16)&1u); return (u16)(r>>16); }

DEV uint32_t pk2(float a, float b){
  return (uint32_t)f2bf(a) | ((uint32_t)f2bf(b)<<16);
}

// packed f32 pair -> 2x bf16 via HW cvt_pk (1 VALU inst, RNE)
DEV uint32_t cvtpk(float a, float b){
  uint32_t r;
  asm("v_cvt_pk_bf16_f32 %0, %1, %2" : "=v"(r) : "v"(a), "v"(b));
  return r;
}

// cross-half (lane<32 <-> lane>=32) pairwise exchange
DEV void xswap(uint32_t a, uint32_t b, int hi, uint32_t& ra, uint32_t& rb){
#if __has_builtin(__builtin_amdgcn_permlane32_swap)
  auto r = __builtin_amdgcn_permlane32_swap((int)a, (int)b, false, false);
  ra = (uint32_t)r[0]; rb = (uint32_t)r[1];
#else
  uint32_t sa = (uint32_t)__shfl_xor((int)a, 32);
  uint32_t sb = (uint32_t)__shfl_xor((int)b, 32);
  ra = hi ? sb : a;
  rb = hi ? b  : sa;
#endif
}

DEV void gload_lds16(const u16* g, u16* l){
  __builtin_amdgcn_global_load_lds((gas_t*)g, (las_t*)l, 16, 0, 0);
}

// ---------------- fused fp32 -> bf16 convert (3 segments, 1 launch) ----------------
__global__ void cvt_all(const float* __restrict__ s1, u16* __restrict__ d1,
                        const float* __restrict__ s2, u16* __restrict__ d2,
                        const float* __restrict__ s3, u16* __restrict__ d3)
{
  const int n1 = 1048576, n2 = 786432;
  int i = blockIdx.x*256 + threadIdx.x;  // grid 8192
  const float* src; u16* dst; int j;
  if(i < n1){ src = s1; dst = d1; j = i; }
  else if(i < n1+n2){ src = s2; dst = d2; j = i - n1; }
  else { src = s3; dst = d3; j = i - n1 - n2; }
  float4 v = ((const float4*)src)[j];
  ushort4 o; o.x=f2bf(v.x); o.y=f2bf(v.y); o.z=f2bf(v.z); o.w=f2bf(v.w);
  ((ushort4*)dst)[j] = o;
}

// ---------------- 128x128-tile bf16 GEMM (r15-proven) ----------------
template<int OUT_F32, int SWZ>
__global__ __launch_bounds__(256,3)
void gemm_bt(const u16* __restrict__ A, const u16* __restrict__ Bw,
             const float* __restrict__ bias, void* __restrict__ Cp, int N)
{
  constexpr int BK = 32, KSTEPS = 1024/BK;
  __shared__ __align__(16) u16 pool[3*8192];
  const int tid = threadIdx.x, w = tid>>6, l = tid&63;
  const int a = l&15, g = l>>4;
  int bx, by;
  if(SWZ){
    const int bid = blockIdx.x;
    const int st = bid >> 6, q = bid & 63;
    bx = (st % 3)*8 + (q & 7);
    by = (st / 3)*8 + (q >> 3);
  } else {
    bx = blockIdx.x; by = blockIdx.y;
  }
  const int m0 = by*128, n0 = bx*128;
  const int wr = w>>1, wc = w&1;
  f32x4 zero = {0.f,0.f,0.f,0.f};
  f32x4 acc[4][4];
  #pragma unroll
  for(int m=0;m<4;m++) for(int n=0;n<4;n++) acc[m][n]=zero;

  const int srow = l>>2, scol = (l&3)*8;
  const u16* Ag = A  + (size_t)(m0 + w*32 + srow)*1024 + scol;
  const u16* Bg = Bw + (size_t)(n0 + w*32 + srow)*1024 + scol;

#define STAGE(KIDX, BUF) {                                        \
    u16* ab = pool + (BUF)*8192 + w*1024;                         \
    u16* bb = pool + (BUF)*8192 + 4096 + w*1024;                  \
    gload_lds16(Ag + (KIDX)*BK,           ab);                    \
    gload_lds16(Ag + (KIDX)*BK + 16*1024, ab + 512);              \
    gload_lds16(Bg + (KIDX)*BK,           bb);                    \
    gload_lds16(Bg + (KIDX)*BK + 16*1024, bb + 512);              \
  }

  STAGE(0, 0);
  STAGE(1, 1);

  int bc = 0, bn = 2;
  for(int kt=0; kt<KSTEPS; ++kt){
    if(kt+1 < KSTEPS) asm volatile("s_waitcnt vmcnt(4)" ::: "memory");
    else              asm volatile("s_waitcnt vmcnt(0)" ::: "memory");
    __builtin_amdgcn_s_barrier();
    __builtin_amdgcn_sched_barrier(0);

    if(kt+2 < KSTEPS) STAGE(kt+2, bn);

    const u16* AsB = pool + bc*8192;
    const u16* BsB = AsB + 4096;
    bf16x8 af[4], bf[4];
    #pragma unroll
    for(int m=0;m<4;m++) af[m] = *(const bf16x8*)(AsB + (wr*64 + m*16 + a)*BK + g*8);
    #pragma unroll
    for(int n=0;n<4;n++) bf[n] = *(const bf16x8*)(BsB + (wc*64 + n*16 + a)*BK + g*8);
    #pragma unroll
    for(int m=0;m<4;m++)
      #pragma unroll
      for(int n=0;n<4;n++)
        acc[m][n] = __builtin_amdgcn_mfma_f32_16x16x32_bf16(af[m], bf[n], acc[m][n], 0,0,0);

    bc = (bc==2) ? 0 : bc+1;
    bn = (bn==2) ? 0 : bn+1;
  }
#undef STAGE

  if(OUT_F32){
    #pragma unroll
    for(int n=0;n<4;n++){
      int col = n0 + wc*64 + n*16 + a;
      float bv = bias[col];
      #pragma unroll
      for(int m=0;m<4;m++){
        int row = m0 + wr*64 + m*16 + g*4;
        #pragma unroll
        for(int r=0;r<4;r++)
          ((float*)Cp)[(size_t)(row+r)*N + col] = acc[m][n][r] + bv;
      }
    }
  } else {
    __syncthreads();
    u16* cw = pool + (size_t)w*4608;
    #pragma unroll
    for(int n=0;n<4;n++){
      float bv = bias[n0 + wc*64 + n*16 + a];
      #pragma unroll
      for(int m=0;m<4;m++)
        #pragma unroll
        for(int r=0;r<4;r++)
          cw[(m*16 + g*4 + r)*72 + n*16 + a] = f2bf(acc[m][n][r] + bv);
    }
    u16* Cb = (u16*)Cp + (size_t)(m0 + wr*64)*N + n0 + wc*64;
    #pragma unroll
    for(int rr=0;rr<8;rr++){
      int row = rr*8 + (l>>3);
      uint4 v = *(const uint4*)(cw + row*72 + (l&7)*8);
      *(uint4*)(Cb + (size_t)row*N + (l&7)*8) = v;
    }
  }
}

// ---------------- fused RoPE(q,k) + V-transpose (r15-proven) ----------------
__global__ __launch_bounds__(256,2)
void rope_vt(const u16* __restrict__ qkv, u16* __restrict__ q_r,
             u16* __restrict__ k_r, u16* __restrict__ vt)
{
  __shared__ uint32_t L[64*65];
  const int tid = threadIdx.x;
  const int bh = blockIdx.x & 31;
  const int stile = blockIdx.x >> 5;
  const int b = bh >> 4, h = bh & 15;
  const int s0 = stile*128;

  const int cg = tid & 7, sr = tid >> 3;
  const u16* vsrc = qkv + (size_t)(b*2048 + s0)*3072 + 2048 + h*64 + cg*8;
  union U4 { uint4 v; u16 e[8]; };
  U4 v0a, v1a, v0b, v1b;
  v0a.v = *(const uint4*)(vsrc + (size_t)(sr*2    )*3072);
  v1a.v = *(const uint4*)(vsrc + (size_t)(sr*2 + 1)*3072);
  v0b.v = *(const uint4*)(vsrc + (size_t)(64 + sr*2    )*3072);
  v1b.v = *(const uint4*)(vsrc + (size_t)(64 + sr*2 + 1)*3072);
  #pragma unroll
  for(int jj=0;jj<8;jj++){
    L[(cg*8+jj)*65 + sr]      = (uint32_t)v0a.e[jj] | ((uint32_t)v1a.e[jj]<<16);
    L[(cg*8+jj)*65 + 32 + sr] = (uint32_t)v0b.e[jj] | ((uint32_t)v1b.e[jj]<<16);
  }
  __syncthreads();
  {
    const int w = tid>>6, ln = tid&63;
    u16* dst = vt + (size_t)bh*64*2048 + s0;
    #pragma unroll
    for(int dd=0;dd<16;dd++){
      int d = w*16 + dd;
      *(uint32_t*)(dst + (size_t)d*2048 + ln*2) = L[d*65 + ln];
    }
  }

  const float QSC = 0.18033688011112042f;  // log2(e)/8
  #pragma unroll
  for(int it=0; it<2; ++it){
    int t2 = it*256 + tid;
    int row = t2>>2, gI = t2&3;
    int s = s0 + row;
    int d0 = gI*8;
    const u16* base = qkv + (size_t)(b*2048 + s)*3072 + h*64 + d0;
    union U { uint4 v; u16 e[8]; };
    U q1,q2,k1,k2, oq1,oq2,ok1,ok2;
    q1.v = *(const uint4*)(base);
    q2.v = *(const uint4*)(base+32);
    k1.v = *(const uint4*)(base+1024);
    k2.v = *(const uint4*)(base+1024+32);
    #pragma unroll
    for(int j=0;j<8;j++){
      float d = (float)(d0+j);
      float fr = __expf(-0.28782313662425574f * d);
      float ang = (float)s * fr;
      float sn, cs; sincosf(ang, &sn, &cs);
      float snq = sn*QSC, csq = cs*QSC;
      float x1 = bf2f(q1.e[j]), x2 = bf2f(q2.e[j]);
      oq1.e[j] = f2bf(x1*csq - x2*snq); oq2.e[j] = f2bf(x1*snq + x2*csq);
      x1 = bf2f(k1.e[j]); x2 = bf2f(k2.e[j]);
      ok1.e[j] = f2bf(x1*cs - x2*sn); ok2.e[j] = f2bf(x1*sn + x2*cs);
    }
    size_t o = ((size_t)bh*2048 + s)*64 + d0;
    *(uint4*)(q_r+o) = oq1.v; *(uint4*)(q_r+o+32) = oq2.v;
    *(uint4*)(k_r+o) = ok1.v; *(uint4*)(k_r+o+32) = ok2.v;
  }
}

// ---------------- 32-q-row, 4-way-kv flash attention (makespan halved) ----------------
// Block = 256 thr, 4 waves. All waves share ONE 32-row q-tile; wave w owns the
// kv quarter (kv0 + w*32) of each 128-kv staged super-tile (K[128][64]+VT[64][128],
// 32KB single-buffered). Longest block: 16 rounds (vs 32 in fwd8). Pure-sum softmax;
// 4-way combine = single-phase LDS add. Staging/read maps = fwd10 (r17-debugged).
__global__ __launch_bounds__(256,4)
void attn_fwd11(const u16* __restrict__ Q, const u16* __restrict__ K,
                const u16* __restrict__ VT, u16* __restrict__ O)
{
  __shared__ __align__(16) u16 pool[16384];   // K[128][64] | VT[64][128] (32 KB)
  __shared__ float Ll[3][32];
  const int tid = threadIdx.x, w = tid>>6, ln = tid&63;
  const int lo = ln&31, hi = ln>>5;
  const int b0 = blockIdx.x;            // 2048 blocks, LPT order
  const int bh = b0 & 31;               // head -> XCD bh%8 (matches rope_vt writer)
  const int j  = 63 - (b0 >> 5);        // q-tile 0..63, longest first
  const int q0 = j*32;
  const int nst = (j + 4) >> 2;         // 128-kv super-tiles

  const u16* Qb = Q  + ((size_t)bh*2048 + q0)*64;
  const u16* Kg = K  + (size_t)bh*2048*64;
  const u16* Vg = VT + (size_t)bh*64*2048;

  bf16x8 qf[4];
  #pragma unroll
  for(int s=0;s<4;s++) qf[s] = *(const bf16x8*)(Qb + lo*64 + s*16 + hi*8);

  // K staging map (fwd10): wave w stages K rows w*32..+32
  const u16* srcK = Kg + (size_t)(w*32 + (ln>>3))*64 + ((ln&7)^(ln>>3))*8;
  u16* dstK = pool + (w*32)*64;

  f32x16 oacc0, oacc1, z16;
  #pragma unroll
  for(int r=0;r<16;r++){ oacc0[r]=0.f; oacc1[r]=0.f; z16[r]=0.f; }
  float l_loc = 0.f;
  const int swz = lo&7;                 // 16B-chunk XOR for reads

  for(int t=0; t<nst; ++t){
    const int kv0 = t*128;
    // stage K quarter (4 gloads) + VT quarter (4 gloads)
    #pragma unroll
    for(int i=0;i<4;i++)
      gload_lds16(srcK + (size_t)(kv0 + i*8)*64, dstK + i*8*64);
    #pragma unroll
    for(int i=0;i<4;i++){
      const int d = w*16 + i*4 + (ln>>4);
      const int sc = (ln&15) ^ (d&7);
      gload_lds16(Vg + (size_t)d*2048 + kv0 + sc*8,
                  pool + 8192 + (w*16 + i*4)*128);
    }
    __syncthreads();   // drain + visibility

    const int kva = kv0 + w*32;
    if(kva <= q0 + 31){
      const u16* Kl = pool;
      const u16* Vl = pool + 8192;
      bf16x8 kf[4], vf[4];
      #pragma unroll
      for(int s=0;s<4;s++)
        kf[s] = *(const bf16x8*)(Kl + (w*32+lo)*64 + (((s*2+hi) ^ swz)<<3));
      #pragma unroll
      for(int dt=0;dt<2;dt++)
        #pragma unroll
        for(int s2=0;s2<2;s2++)
          vf[dt*2+s2] = *(const bf16x8*)(Vl + (dt*32+lo)*128 + (((w*4+s2*2+hi) ^ swz)<<3));

      __builtin_amdgcn_s_setprio(1);
      f32x16 st = __builtin_amdgcn_mfma_f32_32x32x16_bf16(kf[0], qf[0], z16, 0,0,0);
      #pragma unroll
      for(int s=1;s<4;s++)
        st = __builtin_amdgcn_mfma_f32_32x32x16_bf16(kf[s], qf[s], st, 0,0,0);
      __builtin_amdgcn_s_setprio(0);

      float p[16];
      #pragma unroll
      for(int r=0;r<16;r++) p[r] = exp2f(st[r]);
      if(kva == q0){   // diagonal subtile: mask kv > q
        #pragma unroll
        for(int r=0;r<16;r++){
          const int kvg = (r&3) + 8*(r>>2) + 4*hi;
          p[r] = (kvg <= lo) ? p[r] : 0.f;
        }
      }

      float sm[8];
      #pragma unroll
      for(int i=0;i<8;i++) sm[i] = p[i] + p[i+8];
      #pragma unroll
      for(int s=4;s>=1;s>>=1)
        #pragma unroll
        for(int i=0;i<s;i++) sm[i] += sm[i+s];
      l_loc += sm[0];

      uint32_t pk[8];
      #pragma unroll
      for(int i=0;i<8;i++) pk[i] = cvtpk(p[2*i], p[2*i+1]);

      union PF { bf16x8 v; uint32_t u[4]; } pf0, pf1;
      xswap(pk[0], pk[2], hi, pf0.u[0], pf0.u[2]);
      xswap(pk[1], pk[3], hi, pf0.u[1], pf0.u[3]);
      xswap(pk[4], pk[6], hi, pf1.u[0], pf1.u[2]);
      xswap(pk[5], pk[7], hi, pf1.u[1], pf1.u[3]);

      __builtin_amdgcn_s_setprio(1);
      oacc0 = __builtin_amdgcn_mfma_f32_32x32x16_bf16(vf[0], pf0.v, oacc0, 0,0,0);
      oacc0 = __builtin_amdgcn_mfma_f32_32x32x16_bf16(vf[1], pf1.v, oacc0, 0,0,0);
      oacc1 = __builtin_amdgcn_mfma_f32_32x32x16_bf16(vf[2], pf0.v, oacc1, 0,0,0);
      oacc1 = __builtin_amdgcn_mfma_f32_32x32x16_bf16(vf[3], pf1.v, oacc1, 0,0,0);
      __builtin_amdgcn_s_setprio(0);
    }
    __syncthreads();   // reads done before restage / combine reuse
  }

  float l_run = l_loc + __shfl_xor(l_loc, 32);

  // ---- 4-way combine (exact add), single phase: waves 1..3 -> slots 0..2 ----
  float* PF = (float*)pool;             // 8192 f32; 3 slots x [64][32] = 6144
  if(w >= 1){
    const int slot = w-1;
    #pragma unroll
    for(int r=0;r<16;r++){
      const int d = 4*hi + (r&3) + 8*(r>>2);
      PF[slot*2048 + d*32 + lo]      = oacc0[r];
      PF[slot*2048 + (d+32)*32 + lo] = oacc1[r];
    }
    if(hi == 0) Ll[slot][lo] = l_run;
  }
  __syncthreads();
  if(w == 0){
    l_run += Ll[0][lo] + Ll[1][lo] + Ll[2][lo];
    #pragma unroll
    for(int r=0;r<16;r++){
      const int d = 4*hi + (r&3) + 8*(r>>2);
      oacc0[r] += PF[d*32 + lo]      + PF[2048 + d*32 + lo]      + PF[4096 + d*32 + lo];
      oacc1[r] += PF[(d+32)*32 + lo] + PF[2048 + (d+32)*32 + lo] + PF[4096 + (d+32)*32 + lo];
    }
    const float invl = 1.f / l_run;
    const int row_g = (bh>>4)*2048 + q0 + lo;
    u16* Ob = O + (size_t)row_g*1024 + (bh&15)*64;
    #pragma unroll
    for(int g2=0; g2<4; g2++){
      uint2 pr;
      pr.x = pk2(oacc0[4*g2+0]*invl, oacc0[4*g2+1]*invl);
      pr.y = pk2(oacc0[4*g2+2]*invl, oacc0[4*g2+3]*invl);
      *(uint2*)(Ob + 8*g2 + 4*hi) = pr;
    }
    #pragma unroll
    for(int g2=0; g2<4; g2++){
      uint2 pr;
      pr.x = pk2(oacc1[4*g2+0]*invl, oacc1[4*g2+1]*invl);
      pr.y = pk2(oacc1[4*g2+2]*invl, oacc1[4*g2+3]*invl);
      *(uint2*)(Ob + 32 + 8*g2 + 4*hi) = pr;
    }
  }
}

extern "C" void kernel_launch(void* const* d_in, const int* in_sizes, int n_in,
                              void* d_out, int out_size, void* d_ws, size_t ws_size,
                              hipStream_t stream)
{
  const float* x      = (const float*)d_in[0];
  const float* qkv_w  = (const float*)d_in[1];
  const float* qkv_b  = (const float*)d_in[2];
  const float* proj_w = (const float*)d_in[3];
  const float* proj_b = (const float*)d_in[4];
  float* out = (float*)d_out;
  char* ws = (char*)d_ws;

  u16* xb    = (u16*)(ws);                          // 8 MB (reused as attn O)
  u16* wqkv  = (u16*)(ws + 8388608);                // 6 MB
  u16* wproj = (u16*)(ws + 8388608 + 6291456);      // 2 MB
  u16* qkvr  = (u16*)(ws + 16777216);               // 24 MB
  u16* q_r   = (u16*)(ws + 41943040);               // 8 MB
  u16* k_r   = q_r + 4194304;                       // 8 MB
  u16* vt    = k_r + 4194304;                       // 8 MB (V^T)
  u16* o_b   = xb;

  cvt_all<<<8192,256,0,stream>>>(x, xb, qkv_w, wqkv, proj_w, wproj);

  gemm_bt<0,1><<<768,256,0,stream>>>(xb, wqkv, qkv_b, qkvr, 3072);

  rope_vt<<<512,256,0,stream>>>(qkvr, q_r, k_r, vt);

  attn_fwd11<<<2048,256,0,stream>>>(q_r, k_r, vt, o_b);

  dim3 gC(8,32);
  gemm_bt<1,0><<<gC,256,0,stream>>>(o_b, wproj, proj_b, out, 1024);
}

// Round 21
// 104.435 us; speedup vs baseline: 1.0494x; 1.0494x over previous
//
#include <hip/hip_runtime.h>
#include <hip/hip_bf16.h>
#include <stdint.h>

typedef unsigned short u16;
typedef __attribute__((ext_vector_type(8))) short bf16x8;
typedef __attribute__((ext_vector_type(4))) float f32x4;
typedef __attribute__((ext_vector_type(16))) float f32x16;

typedef __attribute__((address_space(1))) const void gas_t;
typedef __attribute__((address_space(3))) void las_t;

#define DEV __device__ __forceinline__

DEV float bf2f(u16 v){ union{uint32_t u; float f;} x; x.u = ((uint32_t)v)<<16; return x.f; }
DEV u16 f2bf(float f){ union{float f; uint32_t u;} x; x.f=f; uint32_t r = x.u + 0x7fff + ((x.u>>16)&1u); return (u16)(r>>16); }

DEV uint32_t pk2(float a, float b){
  return (uint32_t)f2bf(a) | ((uint32_t)f2bf(b)<<16);
}

// packed f32 pair -> 2x bf16 via HW cvt_pk (1 VALU inst, RNE)
DEV uint32_t cvtpk(float a, float b){
  uint32_t r;
  asm("v_cvt_pk_bf16_f32 %0, %1, %2" : "=v"(r) : "v"(a), "v"(b));
  return r;
}

// cross-half (lane<32 <-> lane>=32) pairwise exchange
DEV void xswap(uint32_t a, uint32_t b, int hi, uint32_t& ra, uint32_t& rb){
#if __has_builtin(__builtin_amdgcn_permlane32_swap)
  auto r = __builtin_amdgcn_permlane32_swap((int)a, (int)b, false, false);
  ra = (uint32_t)r[0]; rb = (uint32_t)r[1];
#else
  uint32_t sa = (uint32_t)__shfl_xor((int)a, 32);
  uint32_t sb = (uint32_t)__shfl_xor((int)b, 32);
  ra = hi ? sb : a;
  rb = hi ? b  : sa;
#endif
}

DEV void gload_lds16(const u16* g, u16* l){
  __builtin_amdgcn_global_load_lds((gas_t*)g, (las_t*)l, 16, 0, 0);
}

// ---------------- fused fp32 -> bf16 convert (3 segments, 1 launch) ----------------
__global__ void cvt_all(const float* __restrict__ s1, u16* __restrict__ d1,
                        const float* __restrict__ s2, u16* __restrict__ d2,
                        const float* __restrict__ s3, u16* __restrict__ d3)
{
  const int n1 = 1048576, n2 = 786432;
  int i = blockIdx.x*256 + threadIdx.x;  // grid 8192
  const float* src; u16* dst; int j;
  if(i < n1){ src = s1; dst = d1; j = i; }
  else if(i < n1+n2){ src = s2; dst = d2; j = i - n1; }
  else { src = s3; dst = d3; j = i - n1 - n2; }
  float4 v = ((const float4*)src)[j];
  ushort4 o; o.x=f2bf(v.x); o.y=f2bf(v.y); o.z=f2bf(v.z); o.w=f2bf(v.w);
  ((ushort4*)dst)[j] = o;
}

// ---------------- 256x128-tile bf16 GEMM (qkv): AI=85 FLOP/B, 2 blocks/CU ----------------
// 8 waves (4m x 2n, per-wave 64x64 out). Depth-2 counted-vmcnt(3) pipeline, 3 LDS bufs.
// 8x8 supertile block ordering. Vectorized bf16 epilogue via per-wave LDS tile.
__global__ __launch_bounds__(512,4)
void gemm_qkv256(const u16* __restrict__ A, const u16* __restrict__ Bw,
                 const float* __restrict__ bias, u16* __restrict__ Cp, int N)
{
  constexpr int BK = 32, KSTEPS = 1024/BK;
  __shared__ __align__(16) u16 pool[3*12288];   // buf b: A[256][32] @ b*12288, B[128][32] @ +8192
  const int tid = threadIdx.x, w = tid>>6, l = tid&63;
  const int a = l&15, g = l>>4;
  const int bid = blockIdx.x;            // 384 = 6 supertiles x 64
  const int st = bid >> 6, q = bid & 63;
  const int bx = (st % 3)*8 + (q & 7);   // 0..23
  const int by = (st / 3)*8 + (q >> 3);  // 0..15
  const int m0 = by*256, n0 = bx*128;
  const int wr = w>>1, wc = w&1;
  f32x4 zero = {0.f,0.f,0.f,0.f};
  f32x4 acc[4][4];
  #pragma unroll
  for(int m=0;m<4;m++) for(int n=0;n<4;n++) acc[m][n]=zero;

  const int srow = l>>2, scol = (l&3)*8;
  const u16* Ag = A  + (size_t)(m0 + w*32 + srow)*1024 + scol;   // wave: A rows w*32..+31
  const u16* Bg = Bw + (size_t)(n0 + w*16 + srow)*1024 + scol;   // wave: B rows w*16..+15

#define STAGE(KIDX, BUF) {                                        \
    u16* ab = pool + (BUF)*12288 + w*1024;                        \
    u16* bb = pool + (BUF)*12288 + 8192 + w*512;                  \
    gload_lds16(Ag + (KIDX)*BK,           ab);                    \
    gload_lds16(Ag + (KIDX)*BK + 16*1024, ab + 512);              \
    gload_lds16(Bg + (KIDX)*BK,           bb);                    \
  }

  STAGE(0, 0);
  STAGE(1, 1);

  int bc = 0, bn = 2;
  for(int kt=0; kt<KSTEPS; ++kt){
    if(kt+1 < KSTEPS) asm volatile("s_waitcnt vmcnt(3)" ::: "memory");
    else              asm volatile("s_waitcnt vmcnt(0)" ::: "memory");
    __builtin_amdgcn_s_barrier();
    __builtin_amdgcn_sched_barrier(0);

    if(kt+2 < KSTEPS) STAGE(kt+2, bn);

    const u16* AsB = pool + bc*12288;
    const u16* BsB = AsB + 8192;
    bf16x8 af[4], bf[4];
    #pragma unroll
    for(int m=0;m<4;m++) af[m] = *(const bf16x8*)(AsB + (wr*64 + m*16 + a)*BK + g*8);
    #pragma unroll
    for(int n=0;n<4;n++) bf[n] = *(const bf16x8*)(BsB + (wc*64 + n*16 + a)*BK + g*8);
    #pragma unroll
    for(int m=0;m<4;m++)
      #pragma unroll
      for(int n=0;n<4;n++)
        acc[m][n] = __builtin_amdgcn_mfma_f32_16x16x32_bf16(af[m], bf[n], acc[m][n], 0,0,0);

    bc = (bc==2) ? 0 : bc+1;
    bn = (bn==2) ? 0 : bn+1;
  }
#undef STAGE

  // vectorized bf16 epilogue: acc -> per-wave LDS [64][72] -> dwordx4 stores
  __syncthreads();   // pipeline bufs dead; reuse pool (8 waves x 4608 u16 = 36864 = pool size)
  u16* cw = pool + (size_t)w*4608;
  #pragma unroll
  for(int n=0;n<4;n++){
    float bv = bias[n0 + wc*64 + n*16 + a];
    #pragma unroll
    for(int m=0;m<4;m++)
      #pragma unroll
      for(int r=0;r<4;r++)
        cw[(m*16 + g*4 + r)*72 + n*16 + a] = f2bf(acc[m][n][r] + bv);
  }
  u16* Cb = Cp + (size_t)(m0 + wr*64)*N + n0 + wc*64;
  #pragma unroll
  for(int rr=0;rr<8;rr++){
    int row = rr*8 + (l>>3);
    uint4 v = *(const uint4*)(cw + row*72 + (l&7)*8);
    *(uint4*)(Cb + (size_t)row*N + (l&7)*8) = v;
  }
}

// ---------------- 128x128-tile bf16 GEMM (f32 out) for proj ----------------
template<int OUT_F32, int SWZ>
__global__ __launch_bounds__(256,3)
void gemm_bt(const u16* __restrict__ A, const u16* __restrict__ Bw,
             const float* __restrict__ bias, void* __restrict__ Cp, int N)
{
  constexpr int BK = 32, KSTEPS = 1024/BK;
  __shared__ __align__(16) u16 pool[3*8192];
  const int tid = threadIdx.x, w = tid>>6, l = tid&63;
  const int a = l&15, g = l>>4;
  int bx, by;
  if(SWZ){
    const int bid = blockIdx.x;
    const int st = bid >> 6, q = bid & 63;
    bx = (st % 3)*8 + (q & 7);
    by = (st / 3)*8 + (q >> 3);
  } else {
    bx = blockIdx.x; by = blockIdx.y;
  }
  const int m0 = by*128, n0 = bx*128;
  const int wr = w>>1, wc = w&1;
  f32x4 zero = {0.f,0.f,0.f,0.f};
  f32x4 acc[4][4];
  #pragma unroll
  for(int m=0;m<4;m++) for(int n=0;n<4;n++) acc[m][n]=zero;

  const int srow = l>>2, scol = (l&3)*8;
  const u16* Ag = A  + (size_t)(m0 + w*32 + srow)*1024 + scol;
  const u16* Bg = Bw + (size_t)(n0 + w*32 + srow)*1024 + scol;

#define STAGE(KIDX, BUF) {                                        \
    u16* ab = pool + (BUF)*8192 + w*1024;                         \
    u16* bb = pool + (BUF)*8192 + 4096 + w*1024;                  \
    gload_lds16(Ag + (KIDX)*BK,           ab);                    \
    gload_lds16(Ag + (KIDX)*BK + 16*1024, ab + 512);              \
    gload_lds16(Bg + (KIDX)*BK,           bb);                    \
    gload_lds16(Bg + (KIDX)*BK + 16*1024, bb + 512);              \
  }

  STAGE(0, 0);
  STAGE(1, 1);

  int bc = 0, bn = 2;
  for(int kt=0; kt<KSTEPS; ++kt){
    if(kt+1 < KSTEPS) asm volatile("s_waitcnt vmcnt(4)" ::: "memory");
    else              asm volatile("s_waitcnt vmcnt(0)" ::: "memory");
    __builtin_amdgcn_s_barrier();
    __builtin_amdgcn_sched_barrier(0);

    if(kt+2 < KSTEPS) STAGE(kt+2, bn);

    const u16* AsB = pool + bc*8192;
    const u16* BsB = AsB + 4096;
    bf16x8 af[4], bf[4];
    #pragma unroll
    for(int m=0;m<4;m++) af[m] = *(const bf16x8*)(AsB + (wr*64 + m*16 + a)*BK + g*8);
    #pragma unroll
    for(int n=0;n<4;n++) bf[n] = *(const bf16x8*)(BsB + (wc*64 + n*16 + a)*BK + g*8);
    #pragma unroll
    for(int m=0;m<4;m++)
      #pragma unroll
      for(int n=0;n<4;n++)
        acc[m][n] = __builtin_amdgcn_mfma_f32_16x16x32_bf16(af[m], bf[n], acc[m][n], 0,0,0);

    bc = (bc==2) ? 0 : bc+1;
    bn = (bn==2) ? 0 : bn+1;
  }
#undef STAGE

  if(OUT_F32){
    #pragma unroll
    for(int n=0;n<4;n++){
      int col = n0 + wc*64 + n*16 + a;
      float bv = bias[col];
      #pragma unroll
      for(int m=0;m<4;m++){
        int row = m0 + wr*64 + m*16 + g*4;
        #pragma unroll
        for(int r=0;r<4;r++)
          ((float*)Cp)[(size_t)(row+r)*N + col] = acc[m][n][r] + bv;
      }
    }
  } else {
    __syncthreads();
    u16* cw = pool + (size_t)w*4608;
    #pragma unroll
    for(int n=0;n<4;n++){
      float bv = bias[n0 + wc*64 + n*16 + a];
      #pragma unroll
      for(int m=0;m<4;m++)
        #pragma unroll
        for(int r=0;r<4;r++)
          cw[(m*16 + g*4 + r)*72 + n*16 + a] = f2bf(acc[m][n][r] + bv);
    }
    u16* Cb = (u16*)Cp + (size_t)(m0 + wr*64)*N + n0 + wc*64;
    #pragma unroll
    for(int rr=0;rr<8;rr++){
      int row = rr*8 + (l>>3);
      uint4 v = *(const uint4*)(cw + row*72 + (l&7)*8);
      *(uint4*)(Cb + (size_t)row*N + (l&7)*8) = v;
    }
  }
}

// ---------------- fused RoPE(q,k) + V-transpose (r15-proven) ----------------
__global__ __launch_bounds__(256,2)
void rope_vt(const u16* __restrict__ qkv, u16* __restrict__ q_r,
             u16* __restrict__ k_r, u16* __restrict__ vt)
{
  __shared__ uint32_t L[64*65];
  const int tid = threadIdx.x;
  const int bh = blockIdx.x & 31;
  const int stile = blockIdx.x >> 5;
  const int b = bh >> 4, h = bh & 15;
  const int s0 = stile*128;

  const int cg = tid & 7, sr = tid >> 3;
  const u16* vsrc = qkv + (size_t)(b*2048 + s0)*3072 + 2048 + h*64 + cg*8;
  union U4 { uint4 v; u16 e[8]; };
  U4 v0a, v1a, v0b, v1b;
  v0a.v = *(const uint4*)(vsrc + (size_t)(sr*2    )*3072);
  v1a.v = *(const uint4*)(vsrc + (size_t)(sr*2 + 1)*3072);
  v0b.v = *(const uint4*)(vsrc + (size_t)(64 + sr*2    )*3072);
  v1b.v = *(const uint4*)(vsrc + (size_t)(64 + sr*2 + 1)*3072);
  #pragma unroll
  for(int jj=0;jj<8;jj++){
    L[(cg*8+jj)*65 + sr]      = (uint32_t)v0a.e[jj] | ((uint32_t)v1a.e[jj]<<16);
    L[(cg*8+jj)*65 + 32 + sr] = (uint32_t)v0b.e[jj] | ((uint32_t)v1b.e[jj]<<16);
  }
  __syncthreads();
  {
    const int w = tid>>6, ln = tid&63;
    u16* dst = vt + (size_t)bh*64*2048 + s0;
    #pragma unroll
    for(int dd=0;dd<16;dd++){
      int d = w*16 + dd;
      *(uint32_t*)(dst + (size_t)d*2048 + ln*2) = L[d*65 + ln];
    }
  }

  const float QSC = 0.18033688011112042f;  // log2(e)/8
  #pragma unroll
  for(int it=0; it<2; ++it){
    int t2 = it*256 + tid;
    int row = t2>>2, gI = t2&3;
    int s = s0 + row;
    int d0 = gI*8;
    const u16* base = qkv + (size_t)(b*2048 + s)*3072 + h*64 + d0;
    union U { uint4 v; u16 e[8]; };
    U q1,q2,k1,k2, oq1,oq2,ok1,ok2;
    q1.v = *(const uint4*)(base);
    q2.v = *(const uint4*)(base+32);
    k1.v = *(const uint4*)(base+1024);
    k2.v = *(const uint4*)(base+1024+32);
    #pragma unroll
    for(int j=0;j<8;j++){
      float d = (float)(d0+j);
      float fr = __expf(-0.28782313662425574f * d);
      float ang = (float)s * fr;
      float sn, cs; sincosf(ang, &sn, &cs);
      float snq = sn*QSC, csq = cs*QSC;
      float x1 = bf2f(q1.e[j]), x2 = bf2f(q2.e[j]);
      oq1.e[j] = f2bf(x1*csq - x2*snq); oq2.e[j] = f2bf(x1*snq + x2*csq);
      x1 = bf2f(k1.e[j]); x2 = bf2f(k2.e[j]);
      ok1.e[j] = f2bf(x1*cs - x2*sn); ok2.e[j] = f2bf(x1*sn + x2*cs);
    }
    size_t o = ((size_t)bh*2048 + s)*64 + d0;
    *(uint4*)(q_r+o) = oq1.v; *(uint4*)(q_r+o+32) = oq2.v;
    *(uint4*)(k_r+o) = ok1.v; *(uint4*)(k_r+o+32) = ok2.v;
  }
}

// ---------------- kv-half-split + q-shared LDS flash attention (r15-proven) ----------------
__global__ __launch_bounds__(256,4)
void attn_fwd8(const u16* __restrict__ Q, const u16* __restrict__ K,
               const u16* __restrict__ VT, u16* __restrict__ O)
{
  __shared__ __align__(16) u16 Ks[2][64][64];   // [buf][kv][d]
  __shared__ __align__(16) u16 Vs[2][64][64];   // [buf][d][kv]
  const int tid = threadIdx.x, w = tid>>6, ln = tid&63;
  const int lo = ln&31, hi = ln>>5;
  const int wq = w>>1, wk = w&1;
  const int b0 = blockIdx.x;            // 1024 blocks, LPT order
  const int bh = b0 & 31;               // head -> XCD bh%8
  const int j64 = 31 - (b0 >> 5);       // longest first
  const int q0 = j64*64 + wq*32;
  const int nt = j64 + 1;

  const u16* Qb = Q  + ((size_t)bh*2048 + q0)*64;
  const u16* Kb = K  + (size_t)bh*2048*64;
  const u16* Vt = VT + (size_t)bh*64*2048;

  bf16x8 qf[4];
  #pragma unroll
  for(int s=0;s<4;s++) qf[s] = *(const bf16x8*)(Qb + lo*64 + s*16 + hi*8);

  const int rsub = ln>>3;
  const int coloff = ((ln&7) ^ rsub) * 8;       // u16, pre-swizzled source col
  const int wrow = (w&1)*32;
  const size_t rstride = (w<2) ? 64 : 2048;
  const u16* src0 = (w<2) ? (Kb + (size_t)(wrow+rsub)*64 + coloff)
                          : (Vt + (size_t)(wrow+rsub)*2048 + coloff);
  u16* ldsw = (w<2) ? (&Ks[0][0][0] + wrow*64) : (&Vs[0][0][0] + wrow*64);

  f32x16 oacc0, oacc1, z16;
  #pragma unroll
  for(int r=0;r<16;r++){ oacc0[r]=0.f; oacc1[r]=0.f; z16[r]=0.f; }
  float l_loc = 0.f;
  const int swz = (lo&7)<<4;                    // byte XOR for reads

  #pragma unroll
  for(int g=0;g<4;g++) gload_lds16(src0 + (size_t)g*8*rstride, ldsw + g*512);
  __syncthreads();

  int buf = 0;
  for(int t=0; t<nt; ++t){
    if(t+1 < nt){
      const size_t koff = (w<2) ? (size_t)(t+1)*64*64 : (size_t)(t+1)*64;
      u16* dst = ldsw + (buf^1)*4096;
      #pragma unroll
      for(int g=0;g<4;g++) gload_lds16(src0 + koff + (size_t)g*8*rstride, dst + g*512);
    }

    const int kv32 = t*64 + wk*32;
    if(kv32 <= q0 + 31){
      const u16* KsB = &Ks[buf][0][0];
      const u16* VsB = &Vs[buf][0][0];
      bf16x8 kf[4], vf[4];
      #pragma unroll
      for(int s=0;s<4;s++)
        kf[s] = *(const bf16x8*)(KsB + (wk*32+lo)*64 + (((s*32 + hi*16) ^ swz)>>1));
      #pragma unroll
      for(int dt=0;dt<2;dt++)
        #pragma unroll
        for(int s2=0;s2<2;s2++)
          vf[dt*2+s2] = *(const bf16x8*)(VsB + (dt*32+lo)*64 + (((wk*64 + s2*32 + hi*16) ^ swz)>>1));

      f32x16 st = __builtin_amdgcn_mfma_f32_32x32x16_bf16(kf[0], qf[0], z16, 0,0,0);
      #pragma unroll
      for(int s=1;s<4;s++)
        st = __builtin_amdgcn_mfma_f32_32x32x16_bf16(kf[s], qf[s], st, 0,0,0);

      float p[16];
      #pragma unroll
      for(int r=0;r<16;r++) p[r] = exp2f(st[r]);
      if(kv32 == q0){
        #pragma unroll
        for(int r=0;r<16;r++){
          const int kvg = (r&3) + 8*(r>>2) + 4*hi;
          p[r] = (kvg <= lo) ? p[r] : 0.f;
        }
      }

      float sm[8];
      #pragma unroll
      for(int i=0;i<8;i++) sm[i] = p[i] + p[i+8];
      #pragma unroll
      for(int s=4;s>=1;s>>=1)
        #pragma unroll
        for(int i=0;i<s;i++) sm[i] += sm[i+s];
      l_loc += sm[0];

      uint32_t pk[8];
      #pragma unroll
      for(int i=0;i<8;i++) pk[i] = cvtpk(p[2*i], p[2*i+1]);

      union PF { bf16x8 v; uint32_t u[4]; } pf0, pf1;
      xswap(pk[0], pk[2], hi, pf0.u[0], pf0.u[2]);
      xswap(pk[1], pk[3], hi, pf0.u[1], pf0.u[3]);
      xswap(pk[4], pk[6], hi, pf1.u[0], pf1.u[2]);
      xswap(pk[5], pk[7], hi, pf1.u[1], pf1.u[3]);

      oacc0 = __builtin_amdgcn_mfma_f32_32x32x16_bf16(vf[0], pf0.v, oacc0, 0,0,0);
      oacc0 = __builtin_amdgcn_mfma_f32_32x32x16_bf16(vf[1], pf1.v, oacc0, 0,0,0);
      oacc1 = __builtin_amdgcn_mfma_f32_32x32x16_bf16(vf[2], pf0.v, oacc1, 0,0,0);
      oacc1 = __builtin_amdgcn_mfma_f32_32x32x16_bf16(vf[3], pf1.v, oacc1, 0,0,0);
    }
    __syncthreads();
    buf ^= 1;
  }

  float l_run = l_loc + __shfl_xor(l_loc, 32);

  float* LoC = (float*)&Ks[0][0][0];   // [2][64][32] f32
  float* LlC = (float*)&Vs[0][0][0];   // [2][32]
  if(wk == 1){
    #pragma unroll
    for(int r=0;r<16;r++){
      const int d = 4*hi + (r&3) + 8*(r>>2);
      LoC[(wq*64 + d   )*32 + lo] = oacc0[r];
      LoC[(wq*64 + d+32)*32 + lo] = oacc1[r];
    }
    if(hi==0) LlC[wq*32 + lo] = l_run;
  }
  __syncthreads();
  if(wk == 0){
    l_run += LlC[wq*32 + lo];
    #pragma unroll
    for(int r=0;r<16;r++){
      const int d = 4*hi + (r&3) + 8*(r>>2);
      oacc0[r] += LoC[(wq*64 + d   )*32 + lo];
      oacc1[r] += LoC[(wq*64 + d+32)*32 + lo];
    }
    const float invl = 1.f / l_run;
    const int row_g = (bh>>4)*2048 + q0 + lo;
    u16* Ob = O + (size_t)row_g*1024 + (bh&15)*64;
    #pragma unroll
    for(int g2=0; g2<4; g2++){
      uint2 pr;
      pr.x = pk2(oacc0[4*g2+0]*invl, oacc0[4*g2+1]*invl);
      pr.y = pk2(oacc0[4*g2+2]*invl, oacc0[4*g2+3]*invl);
      *(uint2*)(Ob + 8*g2 + 4*hi) = pr;
    }
    #pragma unroll
    for(int g2=0; g2<4; g2++){
      uint2 pr;
      pr.x = pk2(oacc1[4*g2+0]*invl, oacc1[4*g2+1]*invl);
      pr.y = pk2(oacc1[4*g2+2]*invl, oacc1[4*g2+3]*invl);
      *(uint2*)(Ob + 32 + 8*g2 + 4*hi) = pr;
    }
  }
}

extern "C" void kernel_launch(void* const* d_in, const int* in_sizes, int n_in,
                              void* d_out, int out_size, void* d_ws, size_t ws_size,
                              hipStream_t stream)
{
  const float* x      = (const float*)d_in[0];
  const float* qkv_w  = (const float*)d_in[1];
  const float* qkv_b  = (const float*)d_in[2];
  const float* proj_w = (const float*)d_in[3];
  const float* proj_b = (const float*)d_in[4];
  float* out = (float*)d_out;
  char* ws = (char*)d_ws;

  u16* xb    = (u16*)(ws);                          // 8 MB (reused as attn O)
  u16* wqkv  = (u16*)(ws + 8388608);                // 6 MB
  u16* wproj = (u16*)(ws + 8388608 + 6291456);      // 2 MB
  u16* qkvr  = (u16*)(ws + 16777216);               // 24 MB
  u16* q_r   = (u16*)(ws + 41943040);               // 8 MB
  u16* k_r   = q_r + 4194304;                       // 8 MB
  u16* vt    = k_r + 4194304;                       // 8 MB (V^T)
  u16* o_b   = xb;

  cvt_all<<<8192,256,0,stream>>>(x, xb, qkv_w, wqkv, proj_w, wproj);

  gemm_qkv256<<<384,512,0,stream>>>(xb, wqkv, qkv_b, qkvr, 3072);

  rope_vt<<<512,256,0,stream>>>(qkvr, q_r, k_r, vt);

  attn_fwd8<<<1024,256,0,stream>>>(q_r, k_r, vt, o_b);

  dim3 gC(8,32);
  gemm_bt<1,0><<<gC,256,0,stream>>>(o_b, wproj, proj_b, out, 1024);
}